// Round 1
// baseline (132.466 us; speedup 1.0000x reference)
//
#include <hip/hip_runtime.h>
#include <math.h>

#define NQ 14
#define NSTATE (1 << NQ)          // 16384
#define NL 2
#define TPB 512
#define PAIRS (NSTATE / 2)        // 8192
#define QUADS (NSTATE / 4)        // 4096
#define NGATES (NQ + NL * NQ)     // 42

// Apply a generic complex 2x2 gate on bit b of the state held in LDS.
__device__ __forceinline__ void apply1q(float* __restrict__ sre, float* __restrict__ sim_,
                                        int b, const float* __restrict__ g, int tid) {
    const int stride = 1 << b;
    const float g00r = g[0], g00i = g[1], g01r = g[2], g01i = g[3];
    const float g10r = g[4], g10i = g[5], g11r = g[6], g11i = g[7];
    #pragma unroll 4
    for (int p = tid; p < PAIRS; p += TPB) {
        const int low = p & (stride - 1);
        const int i0  = ((p >> b) << (b + 1)) | low;
        const int i1  = i0 | stride;
        const float a0r = sre[i0], a0i = sim_[i0];
        const float a1r = sre[i1], a1i = sim_[i1];
        sre[i0]  = g00r * a0r - g00i * a0i + g01r * a1r - g01i * a1i;
        sim_[i0] = g00r * a0i + g00i * a0r + g01r * a1i + g01i * a1r;
        sre[i1]  = g10r * a0r - g10i * a0i + g11r * a1r - g11i * a1i;
        sim_[i1] = g10r * a0i + g10i * a0r + g11r * a1i + g11i * a1r;
    }
}

// CNOT: swap amplitudes (ctrl bit = 1, targ bit = 0) <-> (ctrl=1, targ=1).
__device__ __forceinline__ void cnot(float* __restrict__ sre, float* __restrict__ sim_,
                                     int bc, int bt, int tid) {
    const int blo = (bc < bt) ? bc : bt;
    const int bhi = (bc < bt) ? bt : bc;
    #pragma unroll 4
    for (int p = tid; p < QUADS; p += TPB) {
        int t1  = ((p >> blo) << (blo + 1)) | (p & ((1 << blo) - 1));
        int idx = ((t1 >> bhi) << (bhi + 1)) | (t1 & ((1 << bhi) - 1));
        idx |= (1 << bc);              // control = 1, target = 0
        const int j = idx | (1 << bt); // partner with target = 1
        const float ar = sre[idx], ai = sim_[idx];
        const float br = sre[j],   bi = sim_[j];
        sre[idx] = br; sim_[idx] = bi;
        sre[j]   = ar; sim_[j]   = ai;
    }
}

__global__ __launch_bounds__(TPB, 1)
void qsim_kernel(const float* __restrict__ x, const float* __restrict__ w,
                 float* __restrict__ out) {
    __shared__ float sre[NSTATE];     // 64 KB
    __shared__ float sim_[NSTATE];    // 64 KB
    __shared__ float gcoef[NGATES * 8];
    __shared__ float wred[TPB / 64][NQ];

    const int tid = threadIdx.x;
    const int s   = blockIdx.x;

    // ---- gate coefficient tables (threads 0..41) ----
    if (tid < NQ) {
        // fused encoding gate RZ(theta) @ RY(theta), theta = tanh(x)*pi
        const float th = tanhf(x[s * NQ + tid]) * 3.14159265358979323846f;
        const float h  = 0.5f * th;
        float sn, c;
        sincosf(h, &sn, &c);
        float* g = &gcoef[tid * 8];
        g[0] =  c * c;   g[1] = -c * sn;   // g00 = ph_m * c
        g[2] = -c * sn;  g[3] =  sn * sn;  // g01 = -ph_m * s
        g[4] =  c * sn;  g[5] =  sn * sn;  // g10 = ph_p * s
        g[6] =  c * c;   g[7] =  c * sn;   // g11 = ph_p * c
    } else if (tid < NGATES) {
        // RX(w[l][i]): [[c, -i s], [-i s, c]]
        const int gi = tid - NQ;          // l*NQ + i
        const float h = 0.5f * w[gi];
        float sn, c;
        sincosf(h, &sn, &c);
        float* g = &gcoef[tid * 8];
        g[0] = c;    g[1] = 0.0f;
        g[2] = 0.0f; g[3] = -sn;
        g[4] = 0.0f; g[5] = -sn;
        g[6] = c;    g[7] = 0.0f;
    }

    // ---- init |0...0> ----
    for (int k = tid; k < NSTATE; k += TPB) { sre[k] = 0.0f; sim_[k] = 0.0f; }
    __syncthreads();
    if (tid == 0) sre[0] = 1.0f;
    __syncthreads();

    // ---- encoding layer: per-sample 1q gate on each wire ----
    for (int i = 0; i < NQ; ++i) {
        apply1q(sre, sim_, NQ - 1 - i, &gcoef[i * 8], tid);
        __syncthreads();
    }

    // ---- entangler layers: RX on each wire, then ring of CNOTs ----
    for (int l = 0; l < NL; ++l) {
        for (int i = 0; i < NQ; ++i) {
            apply1q(sre, sim_, NQ - 1 - i, &gcoef[(NQ + l * NQ + i) * 8], tid);
            __syncthreads();
        }
        for (int i = 0; i < NQ; ++i) {
            const int bc = NQ - 1 - i;              // ctrl wire i
            const int bt = NQ - 1 - ((i + 1) % NQ); // targ wire i+1
            cnot(sre, sim_, bc, bt, tid);
            __syncthreads();
        }
    }

    // ---- <Z_i> = sum_k |amp_k|^2 * (bit_{13-i}(k) ? -1 : +1) ----
    float z[NQ];
    #pragma unroll
    for (int i = 0; i < NQ; ++i) z[i] = 0.0f;
    for (int k = tid; k < NSTATE; k += TPB) {
        const float p = sre[k] * sre[k] + sim_[k] * sim_[k];
        #pragma unroll
        for (int i = 0; i < NQ; ++i) {
            z[i] += ((k >> (NQ - 1 - i)) & 1) ? -p : p;
        }
    }
    #pragma unroll
    for (int i = 0; i < NQ; ++i) {
        #pragma unroll
        for (int off = 32; off >= 1; off >>= 1) z[i] += __shfl_down(z[i], off);
    }
    const int lane = tid & 63, wv = tid >> 6;
    if (lane == 0) {
        #pragma unroll
        for (int i = 0; i < NQ; ++i) wred[wv][i] = z[i];
    }
    __syncthreads();
    if (tid < NQ) {
        float acc = 0.0f;
        #pragma unroll
        for (int v = 0; v < TPB / 64; ++v) acc += wred[v][tid];
        out[s * NQ + tid] = acc;
    }
}

extern "C" void kernel_launch(void* const* d_in, const int* in_sizes, int n_in,
                              void* d_out, int out_size, void* d_ws, size_t ws_size,
                              hipStream_t stream) {
    const float* x = (const float*)d_in[0];     // [B, 14] float32
    const float* w = (const float*)d_in[1];     // [2, 14] float32
    float* out = (float*)d_out;                 // [B, 14] float32
    const int batch = in_sizes[0] / NQ;         // 256
    qsim_kernel<<<batch, TPB, 0, stream>>>(x, w, out);
}

// Round 2
// 18.987 us; speedup vs baseline: 6.9768x; 6.9768x over previous
//
#include <hip/hip_runtime.h>
#include <math.h>

#define NQ 14
#define NSTATE (1 << NQ)   // 16384
#define TPB 512

__device__ __forceinline__ float2 cmul(float2 a, float2 b) {
    return make_float2(a.x * b.x - a.y * b.y, a.x * b.y + a.y * b.x);
}

// RX gate (coeffs cw, sw) on local bit P of the 32-amplitude register block.
// new_a = cw*a - i*sw*b ; new_b = -i*sw*a + cw*b
template<int P>
__device__ __forceinline__ void rxgate(float2 (&amp)[32], float cw, float sw) {
    #pragma unroll
    for (int r = 0; r < 32; ++r) {
        if (r & (1 << P)) continue;
        const int j = r | (1 << P);
        const float2 a = amp[r], b = amp[j];
        amp[r] = make_float2(cw * a.x + sw * b.y, cw * a.y - sw * b.x);
        amp[j] = make_float2(sw * a.y + cw * b.x, -sw * a.x + cw * b.y);
    }
}

__global__ __launch_bounds__(TPB, 1)
void qsim_kernel(const float* __restrict__ x, const float* __restrict__ w,
                 float* __restrict__ out) {
    __shared__ float2 st[NSTATE];      // 128 KB swizzled state
    __shared__ float2 u[NQ][2];        // fused per-qubit vectors (Enc+RX layer1 on |0>)
    __shared__ float cw2[NQ], sw2[NQ]; // layer-2 RX coefficients
    __shared__ float wred[TPB / 64][NQ];

    const int t = threadIdx.x;
    const int s = blockIdx.x;

    // ---- per-qubit fused vectors and layer-2 coeffs (threads 0..13) ----
    if (t < NQ) {
        const float th = tanhf(x[s * NQ + t]) * 3.14159265358979323846f;
        float sn, c;
        sincosf(0.5f * th, &sn, &c);
        // Enc column 0: e0 = e^{-i th/2} c = (c^2, -c s); e1 = e^{+i th/2} s = (c s, s^2)
        const float2 e0 = make_float2(c * c, -c * sn);
        const float2 e1 = make_float2(c * sn, sn * sn);
        float sw, cw;
        sincosf(0.5f * w[t], &sw, &cw);                 // layer-1 RX
        u[t][0] = make_float2(cw * e0.x + sw * e1.y, cw * e0.y - sw * e1.x);
        u[t][1] = make_float2(sw * e0.y + cw * e1.x, -sw * e0.x + cw * e1.y);
        float sb, cb;
        sincosf(0.5f * w[NQ + t], &sb, &cb);            // layer-2 RX
        cw2[t] = cb;
        sw2[t] = sb;
    }
    __syncthreads();

    // ---- build post-ring-1 state analytically (layout A: k = t*32 + r) ----
    // psi[k] = prod_i u_i[b_i], b = M^{-1}(k) wires:
    //   b0 = k0^k13, b1 = k1^k0^k13, b_i = k_i^k_{i-1} (i>=2); wire j <-> k bit 13-j
    int kw[9];
    #pragma unroll
    for (int j = 0; j < 9; ++j) kw[j] = (t >> (8 - j)) & 1;

    float2 pref = u[2][kw[2] ^ kw[1]];
    #pragma unroll
    for (int i = 3; i <= 8; ++i) pref = cmul(pref, u[i][kw[i] ^ kw[i - 1]]);

    float2 q01[2];
    q01[0] = cmul(pref, cmul(u[0][kw[0]], u[1][kw[1] ^ kw[0]]));
    q01[1] = cmul(pref, cmul(u[0][kw[0] ^ 1], u[1][kw[1] ^ kw[0] ^ 1]));

    float2 amp[32];
    #pragma unroll
    for (int r = 0; r < 32; ++r) {
        const int k9 = (r >> 4) & 1, k10 = (r >> 3) & 1, k11 = (r >> 2) & 1,
                  k12 = (r >> 1) & 1, k13 = r & 1;
        float2 a = q01[k13];
        a = cmul(a, u[9][k9 ^ kw[8]]);
        a = cmul(a, u[10][k10 ^ k9]);
        a = cmul(a, u[11][k11 ^ k10]);
        a = cmul(a, u[12][k12 ^ k11]);
        a = cmul(a, u[13][k13 ^ k12]);
        amp[r] = a;
    }

    // ---- layer-2 RX, wires 9..13 (k bits 4..0 local) ----
    rxgate<4>(amp, cw2[9], sw2[9]);
    rxgate<3>(amp, cw2[10], sw2[10]);
    rxgate<2>(amp, cw2[11], sw2[11]);
    rxgate<1>(amp, cw2[12], sw2[12]);
    rxgate<0>(amp, cw2[13], sw2[13]);

    // ---- transpose A -> B (local = k bits 5..9), swizzle SW(k)=k^((k>>5)&31) ----
    #pragma unroll
    for (int r = 0; r < 32; ++r) {
        const int k = (t << 5) | r;
        st[k ^ ((k >> 5) & 31)] = amp[r];
    }
    __syncthreads();
    const int lo5 = t & 31, hi4 = t >> 5;
    #pragma unroll
    for (int r = 0; r < 32; ++r) {
        const int k = (hi4 << 10) | (r << 5) | lo5;
        amp[r] = st[k ^ r];
    }

    // ---- layer-2 RX, wires 4..8 (r bit = 8 - wire) ----
    rxgate<4>(amp, cw2[4], sw2[4]);
    rxgate<3>(amp, cw2[5], sw2[5]);
    rxgate<2>(amp, cw2[6], sw2[6]);
    rxgate<1>(amp, cw2[7], sw2[7]);
    rxgate<0>(amp, cw2[8], sw2[8]);

    // ---- transpose B -> C (local = k bits {13..10, 0}) ----
    #pragma unroll
    for (int r = 0; r < 32; ++r) {
        const int k = (hi4 << 10) | (r << 5) | lo5;
        st[k ^ r] = amp[r];
    }
    __syncthreads();
    #pragma unroll
    for (int r = 0; r < 32; ++r) {
        const int k = ((r >> 1) << 10) | (t << 1) | (r & 1);
        amp[r] = st[k ^ ((k >> 5) & 31)];
    }

    // ---- layer-2 RX, wires 0..3 (r bit = 4 - wire) ----
    rxgate<4>(amp, cw2[0], sw2[0]);
    rxgate<3>(amp, cw2[1], sw2[1]);
    rxgate<2>(amp, cw2[2], sw2[2]);
    rxgate<1>(amp, cw2[3], sw2[3]);

    // ---- measurement: <Z_q>_final = sum_k sign_q(k) |amp[k]|^2 ----
    // Final CNOT ring absorbed: O_0 = Z_1..Z_13 (bits 0..12), O_q = Z_0..Z_q
    // (bits 13..13-q). sign = (-1)^popc(k & mask_q).
    float z[NQ];
    #pragma unroll
    for (int q = 0; q < NQ; ++q) z[q] = 0.0f;

    #pragma unroll
    for (int r = 0; r < 32; ++r) {
        const float p = amp[r].x * amp[r].x + amp[r].y * amp[r].y;
        const int kc = ((r >> 1) << 10) | (r & 1);   // compile-time part of k
        #pragma unroll
        for (int q = 0; q < NQ; ++q) {
            const int mask = (q == 0) ? 0x1FFF : (((1 << (q + 1)) - 1) << (13 - q));
            z[q] += (__popc(kc & mask) & 1) ? -p : p;
        }
    }
    const int kt = t << 1;                            // thread part of k
    #pragma unroll
    for (int q = 0; q < NQ; ++q) {
        const int mask = (q == 0) ? 0x1FFF : (((1 << (q + 1)) - 1) << (13 - q));
        if (__popc(kt & mask) & 1) z[q] = -z[q];
    }

    #pragma unroll
    for (int q = 0; q < NQ; ++q) {
        #pragma unroll
        for (int off = 32; off >= 1; off >>= 1) z[q] += __shfl_down(z[q], off);
    }
    const int lane = t & 63, wv = t >> 6;
    if (lane == 0) {
        #pragma unroll
        for (int q = 0; q < NQ; ++q) wred[wv][q] = z[q];
    }
    __syncthreads();
    if (t < NQ) {
        float acc = 0.0f;
        #pragma unroll
        for (int v = 0; v < TPB / 64; ++v) acc += wred[v][t];
        out[s * NQ + t] = acc;
    }
}

extern "C" void kernel_launch(void* const* d_in, const int* in_sizes, int n_in,
                              void* d_out, int out_size, void* d_ws, size_t ws_size,
                              hipStream_t stream) {
    const float* x = (const float*)d_in[0];   // [256, 14] float32
    const float* w = (const float*)d_in[1];   // [2, 14] float32
    float* out = (float*)d_out;               // [256, 14] float32
    const int batch = in_sizes[0] / NQ;       // 256
    qsim_kernel<<<batch, TPB, 0, stream>>>(x, w, out);
}

// Round 3
// 9.633 us; speedup vs baseline: 13.7505x; 1.9709x over previous
//
#include <hip/hip_runtime.h>
#include <math.h>

#define NQ 14
#define TPB 64
#define PI_F 3.14159265358979323846f

__device__ __forceinline__ float2 cmul(float2 a, float2 b) {      // a*b
    return make_float2(a.x * b.x - a.y * b.y, a.x * b.y + a.y * b.x);
}
__device__ __forceinline__ float2 cmulc(float2 a, float2 b) {     // a*conj(b)
    return make_float2(a.x * b.x + a.y * b.y, a.y * b.x - a.x * b.y);
}
__device__ __forceinline__ float2 cadd(float2 a, float2 b) {
    return make_float2(a.x + b.x, a.y + b.y);
}

// Per sample: <Z_q> = sum_{b,b'} prod_i u_i[b_i] conj(u_i[b'_i]) W_i[k'_i, k_i],
// k = Ring1(b): k_j = b_0^..^b_j (j>=1), k_0 = b_1^..^b_13.
// W_i = cos(w2_i) Z + sin(w2_i) Y for i in S_q else I, where S_q = Ring2-conjugated
// Z_q support: S_0 = {1..13}, S_q = {0..q} (q>=1)  [HW-verified masks, round 2].
// Contract as a chain over (P,P') prefix parities, i = 1..13, wire 0 = boundary.
__global__ __launch_bounds__(TPB, 1)
void qsim_kernel(const float* __restrict__ x, const float* __restrict__ w,
                 float* __restrict__ out) {
    __shared__ float2 su[NQ][2];   // u_i (Enc+RX-layer1 applied to |0>)
    __shared__ float2 scs[NQ];     // (cos w2_i, sin w2_i)  FULL angle

    const int lane = threadIdx.x;
    const int s = blockIdx.x;

    if (lane < NQ) {
        const float th = tanhf(x[s * NQ + lane]) * PI_F;
        float sn, c;
        sincosf(0.5f * th, &sn, &c);
        const float2 e0 = make_float2(c * c, -c * sn);   // e^{-i th/2} cos
        const float2 e1 = make_float2(c * sn, sn * sn);  // e^{+i th/2} sin
        float sw, cw;
        sincosf(0.5f * w[lane], &sw, &cw);               // layer-1 RX half-angle
        su[lane][0] = make_float2(cw * e0.x + sw * e1.y, cw * e0.y - sw * e1.x);
        su[lane][1] = make_float2(sw * e0.y + cw * e1.x, -sw * e0.x + cw * e1.y);
        float s2, c2;
        sincosf(w[NQ + lane], &s2, &c2);                 // layer-2: FULL angle
        scs[lane] = make_float2(c2, s2);
    }
    __syncthreads();

    // preload everything into registers (loop below is fully unrolled)
    float2 U0[NQ], U1[NQ];
    float CC[NQ], SS[NQ];
    #pragma unroll
    for (int i = 0; i < NQ; ++i) {
        U0[i] = su[i][0];
        U1[i] = su[i][1];
        CC[i] = scs[i].x;
        SS[i] = scs[i].y;
    }

    const int q = lane >> 2;      // observable index (lanes with q>=14 idle)
    const int c = lane & 3;       // chain column = (b0, b'0)
    const int b0 = c >> 1, bp0 = c & 1;

    // g[2P + P'] : chain state, start = basis vector at (P0,P'0) = (b0,b'0)
    float2 g0 = make_float2(c == 0 ? 1.0f : 0.0f, 0.0f);
    float2 g1 = make_float2(c == 1 ? 1.0f : 0.0f, 0.0f);
    float2 g2 = make_float2(c == 2 ? 1.0f : 0.0f, 0.0f);
    float2 g3 = make_float2(c == 3 ? 1.0f : 0.0f, 0.0f);

    #pragma unroll
    for (int i = 1; i < NQ; ++i) {
        const float2 u0 = U0[i], u1 = U1[i];
        // H[p][P'] = sum_{p'} conj(u[P'^p']) * g[2p+p']
        const float2 H00 = cadd(cmulc(g0, u0), cmulc(g1, u1));
        const float2 H01 = cadd(cmulc(g0, u1), cmulc(g1, u0));
        const float2 H10 = cadd(cmulc(g2, u0), cmulc(g3, u1));
        const float2 H11 = cadd(cmulc(g2, u1), cmulc(g3, u0));
        // K[P][P'] = sum_p u[P^p] * H[p][P']
        const float2 K00 = cadd(cmul(u0, H00), cmul(u1, H10));
        const float2 K01 = cadd(cmul(u0, H01), cmul(u1, H11));
        const float2 K10 = cadd(cmul(u1, H00), cmul(u0, H10));
        const float2 K11 = cadd(cmul(u1, H01), cmul(u0, H11));
        // g[2P+P'] = X[P'][P] * K[P][P'],  X = V_i if (q==0 || i<=q) else I
        // V = [[c, -i s], [i s, -c]]
        const bool useV = (q == 0) || (i <= q);
        const float a  = useV ? CC[i] : 1.0f;
        const float d  = useV ? -CC[i] : 1.0f;
        const float sv = useV ? SS[i] : 0.0f;
        g0 = make_float2(a * K00.x, a * K00.y);            // X[0][0] = c
        g1 = make_float2(-sv * K01.y, sv * K01.x);         // X[1][0] = +i s
        g2 = make_float2(sv * K10.y, -sv * K10.x);         // X[0][1] = -i s
        g3 = make_float2(d * K11.x, d * K11.y);            // X[1][1] = -c
    }

    // boundary (wire 0): <Z_q> += Re( u0[b0] conj(u0[b'0]) *
    //                     sum_{P,P'} W0[P'^b'0][P^b0] * g[2P+P'] )
    // W0 = V_0 for q>=1, I for q==0.
    const bool Vb = (q != 0);
    const float a0  = Vb ? CC[0] : 1.0f;
    const float d0  = Vb ? -CC[0] : 1.0f;
    const float sv0 = Vb ? SS[0] : 0.0f;
    const int e = b0 ^ bp0;   // (P^P')==e  <=>  diagonal W entry

    float2 val = make_float2(0.0f, 0.0f);
    {
        // term (P,P'): r = P'^bp0, cl = P^b0
        // diagonal (r==cl): W = (r ? d0 : a0) real
        // off-diag: W = i * (r ? sv0 : -sv0)
        #pragma unroll
        for (int P = 0; P < 2; ++P) {
            #pragma unroll
            for (int Pp = 0; Pp < 2; ++Pp) {
                const float2 gv = (P == 0) ? (Pp == 0 ? g0 : g1)
                                           : (Pp == 0 ? g2 : g3);
                const int r = Pp ^ bp0;
                const bool diag = ((P ^ Pp) == e);
                const float m = r ? d0 : a0;
                const float k = r ? sv0 : -sv0;
                val.x += diag ? m * gv.x : -k * gv.y;
                val.y += diag ? m * gv.y : k * gv.x;
            }
        }
    }
    const float2 w0a = b0 ? U1[0] : U0[0];
    const float2 w0b = bp0 ? U1[0] : U0[0];
    const float2 coeff = cmulc(w0a, w0b);          // u_0[b0] * conj(u_0[b'0])
    float res = coeff.x * val.x - coeff.y * val.y; // Re(coeff * val)

    // sum over the 4 chain columns (lanes q*4 .. q*4+3)
    res += __shfl_xor(res, 1);
    res += __shfl_xor(res, 2);

    if (c == 0 && q < NQ) out[s * NQ + q] = res;
}

extern "C" void kernel_launch(void* const* d_in, const int* in_sizes, int n_in,
                              void* d_out, int out_size, void* d_ws, size_t ws_size,
                              hipStream_t stream) {
    const float* x = (const float*)d_in[0];   // [B, 14] float32
    const float* w = (const float*)d_in[1];   // [2, 14] float32
    float* out = (float*)d_out;               // [B, 14] float32
    const int batch = in_sizes[0] / NQ;       // 256
    qsim_kernel<<<batch, TPB, 0, stream>>>(x, w, out);
}